// Round 6
// baseline (90.684 us; speedup 1.0000x reference)
//
#include <hip/hip_runtime.h>
#include <hip/hip_fp16.h>
#include <cstdint>

#define VOCAB 50000
#define EMB   300
#define SEQ   80
#define HID   128
#define BATCH 4096
#define ROWS  16

typedef __attribute__((ext_vector_type(8))) _Float16 f16x8;
typedef __attribute__((ext_vector_type(4))) float    f32x4;

static __device__ __forceinline__ float fast_tanh(float xv) {
    const float e = __expf(2.f * xv);
    return 1.f - 2.f / (e + 1.f);
}
static __device__ __forceinline__ float f16b2f(unsigned short u) {
    _Float16 h;
    __builtin_memcpy(&h, &u, 2);
    return (float)h;
}
static __device__ __forceinline__ unsigned pack2h(float a, float b) {
    _Float16 ha = (_Float16)a, hb = (_Float16)b;
    unsigned short ua, ub;
    __builtin_memcpy(&ua, &ha, 2);
    __builtin_memcpy(&ub, &hb, 2);
    return (unsigned)ua | ((unsigned)ub << 16);
}

// ---------------------------------------------------------------------------
// k1: P[v][c] = fp16( sum_{k<300} emb[v][k] * Wxh[k][c] )   [50000 x 128]
// Grid 3125 x 512 thr. Block = 16 vocab rows. emb streamed f32 (coalesced),
// converted fp16 on LDS stage; 8 waves x 16 cols, Wxh B-frags in registers.
// Gather/matmul commute: xp = gather(emb,x) @ Wxh = gather(emb @ Wxh, x).
// ---------------------------------------------------------------------------
__global__ __launch_bounds__(512, 2) void k_ptab(
    const float* __restrict__ emb,   // [VOCAB][300]
    const float* __restrict__ Wxh,   // [300][128]
    _Float16*    __restrict__ P)     // [VOCAB][128]
{
    __shared__ __align__(16) unsigned char As[ROWS * 640];   // 16 x 320 fp16
    __shared__ __align__(16) _Float16 Ps[ROWS][HID];

    const int tid  = threadIdx.x;
    const int lane = tid & 63;
    const int wv   = tid >> 6;
    const int r16  = lane & 15;
    const int g    = lane >> 4;
    const int v0   = blockIdx.x * ROWS;
    const int col  = 16 * wv + r16;

    // stage A: 640 16B-chunks (row, f), K padded 300 -> 320 with zeros
    for (int q = tid; q < ROWS * 40; q += 512) {
        const int row = q / 40, f = q % 40;
        const float* src = emb + (size_t)(v0 + row) * EMB + 8 * f;
        float va[8] = {0.f, 0.f, 0.f, 0.f, 0.f, 0.f, 0.f, 0.f};
        if (f <= 36) {
            const float4 u0 = *reinterpret_cast<const float4*>(src);
            const float4 u1 = *reinterpret_cast<const float4*>(src + 4);
            va[0] = u0.x; va[1] = u0.y; va[2] = u0.z; va[3] = u0.w;
            va[4] = u1.x; va[5] = u1.y; va[6] = u1.z; va[7] = u1.w;
        } else if (f == 37) {
            const float4 u0 = *reinterpret_cast<const float4*>(src);
            va[0] = u0.x; va[1] = u0.y; va[2] = u0.z; va[3] = u0.w;
        }
        uint4 o;
        o.x = pack2h(va[0], va[1]); o.y = pack2h(va[2], va[3]);
        o.z = pack2h(va[4], va[5]); o.w = pack2h(va[6], va[7]);
        *reinterpret_cast<uint4*>(&As[row * 640 + ((f ^ (row & 7)) * 16)]) = o;
    }

    // register B-frags: wx[ks][j] = Wxh[32ks+8g+j][col]
    f16x8 wx[10];
    #pragma unroll
    for (int ks = 0; ks < 10; ++ks) {
        f16x8 f;
        #pragma unroll
        for (int j = 0; j < 8; ++j) {
            const int kk = 32 * ks + 8 * g + j;
            f[j] = (_Float16)(kk < EMB ? Wxh[kk * HID + col] : 0.f);
        }
        wx[ks] = f;
    }
    __syncthreads();

    const f32x4 z4 = {0.f, 0.f, 0.f, 0.f};
    f32x4 accA = z4, accB = z4;
    #pragma unroll
    for (int ks = 0; ks < 10; ks += 2) {
        const f16x8 aA = *reinterpret_cast<const f16x8*>(
            &As[r16 * 640 + (((4 * ks + g) ^ (r16 & 7)) * 16)]);
        const f16x8 aB = *reinterpret_cast<const f16x8*>(
            &As[r16 * 640 + (((4 * (ks + 1) + g) ^ (r16 & 7)) * 16)]);
        accA = __builtin_amdgcn_mfma_f32_16x16x32_f16(aA, wx[ks],     accA, 0, 0, 0);
        accB = __builtin_amdgcn_mfma_f32_16x16x32_f16(aB, wx[ks + 1], accB, 0, 0, 0);
    }
    #pragma unroll
    for (int r = 0; r < 4; ++r)
        Ps[4 * g + r][col] = (_Float16)(accA[r] + accB[r]);
    __syncthreads();

    if (tid < 256) {  // coalesced P write: 16 rows x 16 chunks
        const int row = tid >> 4, k = tid & 15;
        *reinterpret_cast<uint4*>(P + (size_t)(v0 + row) * HID + 8 * k) =
            *reinterpret_cast<const uint4*>(&Ps[row][8 * k]);
    }
}

// ---------------------------------------------------------------------------
// k2: recurrence. Block = 16 batch rows x 80 steps, 8 waves (2/SIMD),
// wave owns 16 cols. Per step/wave: 4 b128 h-reads + 4 MFMA (K=128) + tanh;
// xp(t) = P[x[b,t]] gathered (depth-2 reg pipeline) into LDS subtile layout
// X'[w][g][j][16 cols] so each lane's 4 xp values are 4 b16 reads (acc init).
// One raw barrier per step (lgkmcnt-only drain; vmcnt stays counted).
// MFMA 16x16x32 frags: A: lane l = A[l&15][8*(l>>4)+j];
//   B: lane l = B[8*(l>>4)+j][l&15]; D: lane l reg r = D[4*(l>>4)+r][l&15].
// ---------------------------------------------------------------------------
__global__ __launch_bounds__(512, 2) void k_rnn(
    const int*      __restrict__ x,    // [BATCH][SEQ]
    const _Float16* __restrict__ P,    // [VOCAB][HID] fp16
    const float*    __restrict__ Whh,  // [HID][HID]
    const float*    __restrict__ bh,   // [HID]
    const float*    __restrict__ Wd,   // [HID]
    const float*    __restrict__ bd,   // [1]
    float*          __restrict__ out)  // [BATCH]
{
    __shared__ __align__(16) unsigned char Xbuf[2][ROWS * HID * 2]; // 2 x 4 KB
    __shared__ __align__(16) unsigned char Hbuf[2][ROWS * HID * 2]; // 2 x 4 KB
    __shared__ int xidx[ROWS * SEQ];                                 // 5 KB

    const int tid  = threadIdx.x;
    const int lane = tid & 63;
    const int wv   = tid >> 6;     // 0..7
    const int r16  = lane & 15;
    const int g    = lane >> 4;    // 0..3
    const int rb   = blockIdx.x * ROWS;

    for (int q = tid; q < ROWS * SEQ; q += 512) xidx[q] = x[rb * SEQ + q];
    if (tid < 256) {  // zero h parity-0 buffer
        uint4 z = {};
        *reinterpret_cast<uint4*>(&Hbuf[0][tid * 16]) = z;
    }

    const int col = 16 * wv + r16;

    // ---- t-invariant offsets ----
    int h_off[4], w_off[4], x_off[4];
    #pragma unroll
    for (int ks = 0; ks < 4; ++ks)
        h_off[ks] = r16 * 256 + (((4 * ks + g) ^ r16) * 16);
    #pragma unroll
    for (int r = 0; r < 4; ++r) {
        const int rr = 4 * g + r;
        w_off[r] = rr * 256 + (((col >> 3) ^ rr) * 16) + (col & 7) * 2;
        // X' layout: byte = w*512 + g*128 + j*32 + r16*2, XOR bank-spread
        x_off[r] = (wv * 512 + g * 128 + r * 32 + r16 * 2) ^ (((wv + g) & 3) << 4);
    }

    // ---- Whh B-frags in registers ----
    f16x8 wh[4];
    #pragma unroll
    for (int ks = 0; ks < 4; ++ks) {
        f16x8 f;
        #pragma unroll
        for (int j = 0; j < 8; ++j)
            f[j] = (_Float16)Whh[(32 * ks + 8 * g + j) * HID + col];
        wh[ks] = f;
    }
    const float bhv = bh[col];

    // ---- gather assignment (tid<256): row = tid>>4, chunk k = tid&15 ----
    const bool gon  = (tid < 256);
    const int  grow = (tid & 255) >> 4;
    const int  gk   = tid & 15;
    const int  gdst = ((gk >> 1) * 512 + (grow >> 2) * 128 + (grow & 3) * 32 +
                       (gk & 1) * 16) ^ ((((gk >> 1) + (grow >> 2)) & 3) << 4);

    __syncthreads();  // xidx + h0 ready

    // prologue: stage xp(0); issue loads for xp(1)
    if (gon) {
        const uint4 t0 = *reinterpret_cast<const uint4*>(
            P + (size_t)xidx[grow * SEQ] * HID + 8 * gk);
        *reinterpret_cast<uint4*>(&Xbuf[0][gdst]) = t0;
    }
    uint4 cur = {}, nxt = {};
    if (gon) cur = *reinterpret_cast<const uint4*>(
        P + (size_t)xidx[grow * SEQ + 1] * HID + 8 * gk);

    asm volatile("s_waitcnt lgkmcnt(0)" ::: "memory");
    __builtin_amdgcn_s_barrier();
    __builtin_amdgcn_sched_barrier(0);

    const f32x4 z4 = {0.f, 0.f, 0.f, 0.f};

#define STEP(T, PB, CUR, NXT)                                                      \
    {                                                                              \
        /* 1. write prefetched xp(T+1) (loaded a full step ago) */                 \
        if ((T) + 1 < SEQ && gon)                                                  \
            *reinterpret_cast<uint4*>(&Xbuf[(PB) ^ 1][gdst]) = CUR;                \
        /* 2. issue gather for xp(T+2) */                                          \
        if ((T) + 2 < SEQ && gon)                                                  \
            NXT = *reinterpret_cast<const uint4*>(                                 \
                P + (size_t)xidx[grow * SEQ + (T) + 2] * HID + 8 * gk);            \
        /* 3. acc init = xp(T) (D-layout), recurrence MFMA, tanh, h-write */       \
        const unsigned char* xb = &Xbuf[PB][0];                                    \
        const unsigned char* hb = &Hbuf[PB][0];                                    \
        f32x4 accA, accB = z4;                                                     \
        _Pragma("unroll")                                                          \
        for (int r = 0; r < 4; ++r)                                                \
            accA[r] = f16b2f(*reinterpret_cast<const unsigned short*>(             \
                xb + x_off[r]));                                                   \
        const f16x8 h0 = *reinterpret_cast<const f16x8*>(hb + h_off[0]);           \
        const f16x8 h1 = *reinterpret_cast<const f16x8*>(hb + h_off[1]);           \
        const f16x8 h2 = *reinterpret_cast<const f16x8*>(hb + h_off[2]);           \
        const f16x8 h3 = *reinterpret_cast<const f16x8*>(hb + h_off[3]);           \
        accA = __builtin_amdgcn_mfma_f32_16x16x32_f16(h0, wh[0], accA, 0, 0, 0);   \
        accB = __builtin_amdgcn_mfma_f32_16x16x32_f16(h1, wh[1], accB, 0, 0, 0);   \
        accA = __builtin_amdgcn_mfma_f32_16x16x32_f16(h2, wh[2], accA, 0, 0, 0);   \
        accB = __builtin_amdgcn_mfma_f32_16x16x32_f16(h3, wh[3], accB, 0, 0, 0);   \
        unsigned char* hw = &Hbuf[(PB) ^ 1][0];                                    \
        _Pragma("unroll")                                                          \
        for (int r = 0; r < 4; ++r) {                                              \
            const float v = fast_tanh(accA[r] + accB[r] + bhv);                    \
            *reinterpret_cast<_Float16*>(hw + w_off[r]) = (_Float16)v;             \
        }                                                                          \
        asm volatile("s_waitcnt lgkmcnt(0)" ::: "memory");                         \
        __builtin_amdgcn_s_barrier();                                              \
        __builtin_amdgcn_sched_barrier(0);                                         \
    }

    for (int t = 0; t < SEQ; t += 2) {
        STEP(t,     0, cur, nxt);
        STEP(t + 1, 1, nxt, cur);
    }
#undef STEP

    // ---- final dense + sigmoid: h(79) sits in Hbuf[0]; 32 thr per row ----
    const char* hb0 = (const char*)&Hbuf[0][0];
    const int r = tid >> 5;     // 0..15
    const int m = tid & 31;     // cols 4m..4m+3
    const int base = r * 256 + (((m >> 1)) ^ r) * 16 + ((4 * m) & 7) * 2;
    const ushort4 hu = *reinterpret_cast<const ushort4*>(hb0 + base);
    const float4  wd = *reinterpret_cast<const float4*>(&Wd[4 * m]);
    float part = f16b2f(hu.x) * wd.x + f16b2f(hu.y) * wd.y
               + f16b2f(hu.z) * wd.z + f16b2f(hu.w) * wd.w;
    part += __shfl_down(part, 16, 32);
    part += __shfl_down(part, 8, 32);
    part += __shfl_down(part, 4, 32);
    part += __shfl_down(part, 2, 32);
    part += __shfl_down(part, 1, 32);
    if (m == 0) out[rb + r] = 1.f / (1.f + expf(-(part + bd[0])));
}

// ---------------------------------------------------------------------------
extern "C" void kernel_launch(void* const* d_in, const int* in_sizes, int n_in,
                              void* d_out, int out_size, void* d_ws, size_t ws_size,
                              hipStream_t stream)
{
    (void)in_sizes; (void)n_in; (void)out_size; (void)ws_size;
    const int*   x   = (const int*)  d_in[0];
    const float* emb = (const float*)d_in[1];
    const float* Wxh = (const float*)d_in[2];
    const float* Whh = (const float*)d_in[3];
    const float* bh  = (const float*)d_in[4];
    const float* Wd  = (const float*)d_in[5];
    const float* bd  = (const float*)d_in[6];
    float* out = (float*)d_out;

    _Float16* P = (_Float16*)d_ws;   // [VOCAB][128] fp16 = 12.8 MB

    k_ptab<<<VOCAB / ROWS, 512, 0, stream>>>(emb, Wxh, P);
    k_rnn<<<BATCH / ROWS, 512, 0, stream>>>(x, P, Whh, bh, Wd, bd, out);
}

// Round 7
// 72.025 us; speedup vs baseline: 1.2591x; 1.2591x over previous
//
#include <hip/hip_runtime.h>
#include <hip/hip_fp16.h>
#include <cstdint>

#define VOCAB 50000
#define EMB   300
#define SEQ   80
#define HID   128
#define BATCH 4096

typedef __attribute__((ext_vector_type(8))) _Float16 f16x8;
typedef __attribute__((ext_vector_type(4))) float    f32x4;

static __device__ __forceinline__ float fast_tanh(float xv) {
    const float e = __expf(2.f * xv);
    float r;
    asm("v_rcp_f32 %0, %1" : "=v"(r) : "v"(e + 1.f));
    return fmaf(-2.f, r, 1.f);
}
static __device__ __forceinline__ float f16b2f(unsigned short u) {
    _Float16 h; __builtin_memcpy(&h, &u, 2); return (float)h;
}
static __device__ __forceinline__ unsigned pack2h(float a, float b) {
    _Float16 ha = (_Float16)a, hb = (_Float16)b;
    unsigned short ua, ub;
    __builtin_memcpy(&ua, &ha, 2); __builtin_memcpy(&ub, &hb, 2);
    return (unsigned)ua | ((unsigned)ub << 16);
}

// ---------------------------------------------------------------------------
// k_wprep: fragment-ordered fp16 Wxh table. chunk c=(ks,col,g):
//   W2[c][j] = fp16(Wxh[32ks+8g+j][col]), zero-padded past K=300. 80 KB.
// A wave's B-frag load becomes ONE coalesced b128 per (ks, col-tile).
// ---------------------------------------------------------------------------
__global__ __launch_bounds__(256) void k_wprep(const float* __restrict__ Wxh,
                                               _Float16* __restrict__ W2) {
    const int c = blockIdx.x * 256 + threadIdx.x;   // 0..5119
    if (c >= 5120) return;
    const int ks = c >> 9, rem = c & 511, col = rem >> 2, g = rem & 3;
    f16x8 f;
    #pragma unroll
    for (int j = 0; j < 8; ++j) {
        const int k = 32 * ks + 8 * g + j;
        f[j] = (_Float16)(k < EMB ? Wxh[k * HID + col] : 0.f);
    }
    *reinterpret_cast<f16x8*>(W2 + (size_t)c * 8) = f;
}

// ---------------------------------------------------------------------------
// k_ptab: P[v][c] = fp16( emb[v] @ Wxh + bh )  [50000 x 128], bh folded in.
// 256 thr / 4 waves, 64 rows/block (782 blocks ~ 3/CU). Wave owns 32 cols
// (2 col-tiles, A-frag... e-frags reused 2x). e-frags straight from global
// f32 (emb consumed exactly once -> HBM-streaming). Swapped-operand MFMA:
// mfma(wfrag, efrag, acc) -> D lane (g,r16) reg r = P[row r16][col 4g+r]
// (4 consecutive cols, one row) -> b64 LDS stage, coalesced b128 global out.
// ---------------------------------------------------------------------------
__global__ __launch_bounds__(256) void k_ptab(
    const float*    __restrict__ emb,  // [VOCAB][300]
    const _Float16* __restrict__ W2,   // frag table
    const float*    __restrict__ bh,   // [128]
    _Float16*       __restrict__ P)    // [VOCAB][128]
{
    __shared__ __align__(16) unsigned char Ps[16 * 256];   // 4 KB

    const int tid = threadIdx.x, lane = tid & 63, wv = tid >> 6;
    const int r16 = lane & 15, g = lane >> 4;
    const int v0 = blockIdx.x * 64;

    f16x8 wa[10], wb[10];
    #pragma unroll
    for (int ks = 0; ks < 10; ++ks) {
        const int colA = 32 * wv + r16;
        wa[ks] = *reinterpret_cast<const f16x8*>(W2 + ((size_t)ks * 512 + colA * 4 + g) * 8);
        wb[ks] = *reinterpret_cast<const f16x8*>(W2 + ((size_t)ks * 512 + (colA + 16) * 4 + g) * 8);
    }
    const float4 bhA = *reinterpret_cast<const float4*>(bh + 32 * wv + 4 * g);
    const float4 bhB = *reinterpret_cast<const float4*>(bh + 32 * wv + 16 + 4 * g);

    const int psA = r16 * 256 + (((4 * wv + (g >> 1)) ^ r16) & 15) * 16 + (g & 1) * 8;
    const int psB = r16 * 256 + (((4 * wv + 2 + (g >> 1)) ^ r16) & 15) * 16 + (g & 1) * 8;
    const int srow = tid >> 4, schunk = tid & 15;
    const int sbyte = srow * 256 + ((schunk ^ srow) & 15) * 16;

    for (int tile = 0; tile < 4; ++tile) {
        const int row = v0 + tile * 16 + r16;
        const float* rp = emb + (size_t)min(row, VOCAB - 1) * EMB;

        f32x4 accA = {0.f, 0.f, 0.f, 0.f}, accB = {0.f, 0.f, 0.f, 0.f};
        #pragma unroll
        for (int ks = 0; ks < 9; ++ks) {          // ks 0..8: always full
            const int c0 = 32 * ks + 8 * g;
            const float4 u0 = *reinterpret_cast<const float4*>(rp + c0);
            const float4 u1 = *reinterpret_cast<const float4*>(rp + c0 + 4);
            f16x8 ef;
            ef[0]=(_Float16)u0.x; ef[1]=(_Float16)u0.y; ef[2]=(_Float16)u0.z; ef[3]=(_Float16)u0.w;
            ef[4]=(_Float16)u1.x; ef[5]=(_Float16)u1.y; ef[6]=(_Float16)u1.z; ef[7]=(_Float16)u1.w;
            accA = __builtin_amdgcn_mfma_f32_16x16x32_f16(wa[ks], ef, accA, 0, 0, 0);
            accB = __builtin_amdgcn_mfma_f32_16x16x32_f16(wb[ks], ef, accB, 0, 0, 0);
        }
        {   // ks = 9: cols 288+8g.., K-pad past 300
            f16x8 ef;
            #pragma unroll
            for (int j = 0; j < 8; ++j) ef[j] = (_Float16)0.f;
            if (g == 0) {
                const float4 u0 = *reinterpret_cast<const float4*>(rp + 288);
                const float4 u1 = *reinterpret_cast<const float4*>(rp + 292);
                ef[0]=(_Float16)u0.x; ef[1]=(_Float16)u0.y; ef[2]=(_Float16)u0.z; ef[3]=(_Float16)u0.w;
                ef[4]=(_Float16)u1.x; ef[5]=(_Float16)u1.y; ef[6]=(_Float16)u1.z; ef[7]=(_Float16)u1.w;
            } else if (g == 1) {
                const float4 u0 = *reinterpret_cast<const float4*>(rp + 296);
                ef[0]=(_Float16)u0.x; ef[1]=(_Float16)u0.y; ef[2]=(_Float16)u0.z; ef[3]=(_Float16)u0.w;
            }
            accA = __builtin_amdgcn_mfma_f32_16x16x32_f16(wa[9], ef, accA, 0, 0, 0);
            accB = __builtin_amdgcn_mfma_f32_16x16x32_f16(wb[9], ef, accB, 0, 0, 0);
        }

        uint2 oA, oB;
        oA.x = pack2h(accA[0] + bhA.x, accA[1] + bhA.y);
        oA.y = pack2h(accA[2] + bhA.z, accA[3] + bhA.w);
        oB.x = pack2h(accB[0] + bhB.x, accB[1] + bhB.y);
        oB.y = pack2h(accB[2] + bhB.z, accB[3] + bhB.w);
        *reinterpret_cast<uint2*>(&Ps[psA]) = oA;
        *reinterpret_cast<uint2*>(&Ps[psB]) = oB;
        __syncthreads();

        const int orow = v0 + tile * 16 + srow;
        if (orow < VOCAB)
            *reinterpret_cast<uint4*>(P + (size_t)orow * HID + schunk * 8) =
                *reinterpret_cast<const uint4*>(&Ps[sbyte]);
        __syncthreads();
    }
}

// ---------------------------------------------------------------------------
// k_rnn: h(t) = tanh( P[x[b,t]] + h(t-1) @ Whh ), 16 batch rows x 80 steps,
// 8 waves (2/SIMD), wave owns 16 cols. Swapped-operand MFMA (compute h^T):
//   mfma(wh[ks], h_frag[ks], acc) -> D lane (g,r16) reg r =
//   h_new[batch row r16][col 16wv+4g+r]  (4 consecutive cols!)
// -> xp init = ONE ds_read_b64, h write = ONE ds_write_b64 (cvt_pk x2),
// all on the R5-proven XOR-16B swizzle. One raw barrier/step (lgkm-only).
// ---------------------------------------------------------------------------
__global__ __launch_bounds__(512, 2) void k_rnn(
    const int*      __restrict__ x,    // [BATCH][SEQ]
    const _Float16* __restrict__ P,    // [VOCAB][128] fp16 (bh folded)
    const float*    __restrict__ Whh,  // [128][128]
    const float*    __restrict__ Wd,   // [128]
    const float*    __restrict__ bd,   // [1]
    float*          __restrict__ out)  // [BATCH]
{
    __shared__ __align__(16) unsigned char Xb[2][16 * 256];  // xp, fp16
    __shared__ __align__(16) unsigned char Hb[2][16 * 256];  // h, fp16
    __shared__ int xidx[16 * SEQ];

    const int tid = threadIdx.x, lane = tid & 63, wv = tid >> 6;
    const int r16 = lane & 15, g = lane >> 4;
    const int rb = blockIdx.x * 16;

    for (int q = tid; q < 16 * SEQ; q += 512) xidx[q] = x[rb * SEQ + q];
    if (tid < 256) { uint4 z = {}; *reinterpret_cast<uint4*>(&Hb[0][tid * 16]) = z; }

    const int col = 16 * wv + r16;

    int h_rd[4];
    #pragma unroll
    for (int ks = 0; ks < 4; ++ks)
        h_rd[ks] = r16 * 256 + (((4 * ks + g) ^ r16) & 15) * 16;
    const int hw = r16 * 256 + (((2 * wv + (g >> 1)) ^ r16) & 15) * 16 + (g & 1) * 8;

    // Whh fragments (shared A/B lane mapping: k = 32ks+8g+j, other = col)
    f16x8 wh[4];
    #pragma unroll
    for (int ks = 0; ks < 4; ++ks) {
        f16x8 f;
        #pragma unroll
        for (int j = 0; j < 8; ++j)
            f[j] = (_Float16)Whh[(32 * ks + 8 * g + j) * HID + col];
        wh[ks] = f;
    }

    const bool gon  = (tid < 256);
    const int  grow = (tid >> 4) & 15, gk = tid & 15;
    const int  gdst = grow * 256 + ((gk ^ grow) & 15) * 16;

    __syncthreads();  // xidx + h0 ready

    if (gon)
        *reinterpret_cast<uint4*>(&Xb[0][gdst]) = *reinterpret_cast<const uint4*>(
            P + (size_t)xidx[grow * SEQ] * HID + 8 * gk);
    uint4 cur = {}, nxt = {};
    if (gon) cur = *reinterpret_cast<const uint4*>(
        P + (size_t)xidx[grow * SEQ + 1] * HID + 8 * gk);

    asm volatile("s_waitcnt lgkmcnt(0)" ::: "memory");
    __builtin_amdgcn_s_barrier();
    __builtin_amdgcn_sched_barrier(0);

#define STEP(T, PB, CUR, NXT)                                                      \
    {                                                                              \
        if ((T) + 1 < SEQ && gon)                                                  \
            *reinterpret_cast<uint4*>(&Xb[(PB) ^ 1][gdst]) = CUR;                  \
        if ((T) + 2 < SEQ && gon)                                                  \
            NXT = *reinterpret_cast<const uint4*>(                                 \
                P + (size_t)xidx[grow * SEQ + (T) + 2] * HID + 8 * gk);            \
        const uint2 xv = *reinterpret_cast<const uint2*>(&Xb[PB][hw]);             \
        f32x4 accA, accB = {0.f, 0.f, 0.f, 0.f};                                   \
        accA[0] = f16b2f((unsigned short)(xv.x & 0xffff));                         \
        accA[1] = f16b2f((unsigned short)(xv.x >> 16));                            \
        accA[2] = f16b2f((unsigned short)(xv.y & 0xffff));                         \
        accA[3] = f16b2f((unsigned short)(xv.y >> 16));                            \
        const f16x8 h0 = *reinterpret_cast<const f16x8*>(&Hb[PB][h_rd[0]]);        \
        const f16x8 h1 = *reinterpret_cast<const f16x8*>(&Hb[PB][h_rd[1]]);        \
        const f16x8 h2 = *reinterpret_cast<const f16x8*>(&Hb[PB][h_rd[2]]);        \
        const f16x8 h3 = *reinterpret_cast<const f16x8*>(&Hb[PB][h_rd[3]]);        \
        accA = __builtin_amdgcn_mfma_f32_16x16x32_f16(wh[0], h0, accA, 0, 0, 0);   \
        accB = __builtin_amdgcn_mfma_f32_16x16x32_f16(wh[1], h1, accB, 0, 0, 0);   \
        accA = __builtin_amdgcn_mfma_f32_16x16x32_f16(wh[2], h2, accA, 0, 0, 0);   \
        accB = __builtin_amdgcn_mfma_f32_16x16x32_f16(wh[3], h3, accB, 0, 0, 0);   \
        uint2 hv;                                                                  \
        hv.x = pack2h(fast_tanh(accA[0] + accB[0]), fast_tanh(accA[1] + accB[1])); \
        hv.y = pack2h(fast_tanh(accA[2] + accB[2]), fast_tanh(accA[3] + accB[3])); \
        *reinterpret_cast<uint2*>(&Hb[(PB) ^ 1][hw]) = hv;                         \
        asm volatile("s_waitcnt lgkmcnt(0)" ::: "memory");                         \
        __builtin_amdgcn_s_barrier();                                              \
        __builtin_amdgcn_sched_barrier(0);                                         \
    }

    for (int t = 0; t < SEQ; t += 2) {
        STEP(t,     0, cur, nxt);
        STEP(t + 1, 1, nxt, cur);
    }
#undef STEP

    // ---- final dense + sigmoid: h(79) in Hb[0]; 32 threads per batch row ----
    const int r = tid >> 5, m = tid & 31;   // cols 4m..4m+3
    const int fb = r * 256 + (((m >> 1) ^ r) & 15) * 16 + (m & 1) * 8;
    const uint2 hv = *reinterpret_cast<const uint2*>(&Hb[0][fb]);
    const float4 wd = *reinterpret_cast<const float4*>(&Wd[4 * m]);
    float part = f16b2f((unsigned short)(hv.x & 0xffff)) * wd.x
               + f16b2f((unsigned short)(hv.x >> 16))    * wd.y
               + f16b2f((unsigned short)(hv.y & 0xffff)) * wd.z
               + f16b2f((unsigned short)(hv.y >> 16))    * wd.w;
    part += __shfl_down(part, 16, 32);
    part += __shfl_down(part, 8, 32);
    part += __shfl_down(part, 4, 32);
    part += __shfl_down(part, 2, 32);
    part += __shfl_down(part, 1, 32);
    if (m == 0) out[rb + r] = 1.f / (1.f + expf(-(part + bd[0])));
}

// ---------------------------------------------------------------------------
extern "C" void kernel_launch(void* const* d_in, const int* in_sizes, int n_in,
                              void* d_out, int out_size, void* d_ws, size_t ws_size,
                              hipStream_t stream)
{
    (void)in_sizes; (void)n_in; (void)out_size; (void)ws_size;
    const int*   x   = (const int*)  d_in[0];
    const float* emb = (const float*)d_in[1];
    const float* Wxh = (const float*)d_in[2];
    const float* Whh = (const float*)d_in[3];
    const float* bh  = (const float*)d_in[4];
    const float* Wd  = (const float*)d_in[5];
    const float* bd  = (const float*)d_in[6];
    float* out = (float*)d_out;

    _Float16* P  = (_Float16*)d_ws;                          // 12.8 MB
    _Float16* W2 = (_Float16*)((char*)d_ws + 12800000);      // 80 KB frag table

    k_wprep<<<20, 256, 0, stream>>>(Wxh, W2);
    k_ptab<<<(VOCAB + 63) / 64, 256, 0, stream>>>(emb, W2, bh, P);
    k_rnn<<<BATCH / 16, 512, 0, stream>>>(x, P, Whh, Wd, bd, out);
}